// Round 7
// baseline (140.661 us; speedup 1.0000x reference)
//
#include <hip/hip_runtime.h>

#define BINS 256
#define BC_N 24   // B*C = 8*3
#define C_N  3
#define CH   32   // chunks per (row,img): 32*24*2 = 1536 blocks; stride 8192 divides 262144 exactly

// ---------------------------------------------------------------------------
// Kernel 1: per-row 256-bin histograms of dst and ref — REGISTER counting.
//
// LDS atomics/RMWs measured at ~1 lane-op/cyc/CU across r2-r5 (70-87us wall,
// invariant to banking/replication/ILP). This kernel does ZERO LDS work in
// the hot loop: wave-level ballot bit-slicing. Per 64-pixel group, 8 ballots
// give bit-planes B_j of the bins; lane l owns bins {l,l+64,l+128,l+192} and
// counts matching lanes via (B_j ^ t_j) AND-reduce + popc. ~57 VALU / 64 px
// => ~36us floor at 2 VALU instr/cyc/CU.
// bin = floor(x*256) == trunc for x in [0,1); min-clamp for fp safety.
// ---------------------------------------------------------------------------
__global__ __launch_bounds__(256) void hm_hist(const float* __restrict__ dst,
                                               const float* __restrict__ refp,
                                               unsigned int* __restrict__ hist,
                                               int n4_per_row) {
    __shared__ unsigned int wsum[4][BINS];   // per-wave counters merge (4 KB)
    const int t = threadIdx.x;
    const int l = t & 63;                    // lane
    const int w = t >> 6;                    // wave in block

    // t_j: XNOR selector -> (B_j ^ t_j) bit l' == [bin(l')_j == l_j]
    const unsigned long long t0 = (l & 1)  ? 0ull : ~0ull;
    const unsigned long long t1 = (l & 2)  ? 0ull : ~0ull;
    const unsigned long long t2 = (l & 4)  ? 0ull : ~0ull;
    const unsigned long long t3 = (l & 8)  ? 0ull : ~0ull;
    const unsigned long long t4 = (l & 16) ? 0ull : ~0ull;
    const unsigned long long t5 = (l & 32) ? 0ull : ~0ull;

    unsigned int c0 = 0, c1 = 0, c2 = 0, c3 = 0;   // counts for bins l, l+64, l+128, l+192

    const int row = blockIdx.y;
    const float* img = blockIdx.z ? refp : dst;
    const float4* p = reinterpret_cast<const float4*>(img) + (size_t)row * n4_per_row;
    const int stride = CH * 256;             // 8192

    auto grp = [&](float x) {
        int bin = min((int)(x * 256.0f), BINS - 1);
        unsigned long long B0 = __ballot(bin & 1);
        unsigned long long B1 = __ballot(bin & 2);
        unsigned long long B2 = __ballot(bin & 4);
        unsigned long long B3 = __ballot(bin & 8);
        unsigned long long B4 = __ballot(bin & 16);
        unsigned long long B5 = __ballot(bin & 32);
        unsigned long long B6 = __ballot(bin & 64);
        unsigned long long B7 = __ballot(bin & 128);
        unsigned long long m = (B0 ^ t0) & (B1 ^ t1) & (B2 ^ t2)
                             & (B3 ^ t3) & (B4 ^ t4) & (B5 ^ t5);
        unsigned long long n6 = ~B6, n7 = ~B7;
        c0 += (unsigned)__popcll(m & n7 & n6);
        c1 += (unsigned)__popcll(m & n7 & B6);
        c2 += (unsigned)__popcll(m & B7 & n6);
        c3 += (unsigned)__popcll(m & B7 & B6);
    };

    const int nfull = n4_per_row / stride;   // 32 for 1024x1024 rows: NO tail
    int i = blockIdx.x * 256 + t;
    #pragma unroll 4
    for (int it = 0; it < nfull; ++it, i += stride) {
        float4 v = p[i];
        grp(v.x); grp(v.y); grp(v.z); grp(v.w);
    }
    // masked tail (never taken for this shape; ballot-safe: OOB lanes count
    // into bin 0 and lane 0 subtracts them)
    if (nfull * stride < n4_per_row) {
        bool valid = (i < n4_per_row);
        float4 v = make_float4(0.f, 0.f, 0.f, 0.f);
        if (valid) v = p[i];
        unsigned int inv = 64u - (unsigned)__popcll(__ballot(valid));
        grp(v.x); grp(v.y); grp(v.z); grp(v.w);
        if (l == 0) c0 -= 4u * inv;
    }

    // merge 4 waves via LDS (conflict-free: bank = t%32, 2 lanes/bank = free)
    wsum[w][l]       = c0;
    wsum[w][l + 64]  = c1;
    wsum[w][l + 128] = c2;
    wsum[w][l + 192] = c3;
    __syncthreads();

    unsigned int s = wsum[0][t] + wsum[1][t] + wsum[2][t] + wsum[3][t];
    unsigned int* g = hist + ((size_t)blockIdx.z * BC_N + row) * BINS;
    atomicAdd(&g[t], s);
}

// ---------------------------------------------------------------------------
// Kernel 2: fused table + apply. grid = (64, 24), block = 256.
// Table phase (every block recomputes its row's LUT -- cheap, parallel):
//   integer Hillis-Steele inclusive scan (exact; partials <= 2^20) ->
//   CDF = cum / max(total,1e-12) (exact /2^20 -> bit-identical to np's
//   sequential fp32 cumsum) -> parallelized two-pointer:
//     s_i = searchsorted(cdf_ref, cdf_dst[i]); table[i] = max(1, s_i) before
//     first failure; first fail poisons all later entries to 255.
//   table[0]=0, table[255]=255; slut = table/255.
// Apply phase: pix = clip(trunc(dst*255),0,255); out = slut[pix].
// Faithfully preserves the reference's row_sel = b*c indexing bug.
// ---------------------------------------------------------------------------
__global__ __launch_bounds__(256) void hm_apply(const float* __restrict__ dst,
                                                const unsigned int* __restrict__ hist,
                                                float* __restrict__ out,
                                                int n4_per_row) {
    __shared__ unsigned int sd[BINS], sr[BINS];
    __shared__ float cdf_d[BINS], cdf_r[BINS];
    __shared__ float slut[BINS];
    __shared__ int firstFail;

    const int bc = blockIdx.y;
    const int b = bc / C_N;
    const int c = bc - b * C_N;
    const int r = b * c;                 // <-- preserved bug: b*c, not b*C+c
    const int t = threadIdx.x;

    unsigned int xd = hist[(size_t)r * BINS + t];
    unsigned int xr = hist[(size_t)(BC_N + r) * BINS + t];
    if (t == 0) firstFail = BINS;
    sd[t] = xd; sr[t] = xr;
    __syncthreads();

    #pragma unroll
    for (int off = 1; off < BINS; off <<= 1) {
        unsigned int yd = (t >= off) ? sd[t - off] : 0u;
        unsigned int yr = (t >= off) ? sr[t - off] : 0u;
        __syncthreads();
        xd += yd; xr += yr;
        sd[t] = xd; sr[t] = xr;
        __syncthreads();
    }
    float totd = fmaxf((float)sd[BINS - 1], 1e-12f);
    float totr = fmaxf((float)sr[BINS - 1], 1e-12f);
    cdf_d[t] = (float)xd / totd;
    cdf_r[t] = (float)xr / totr;
    __syncthreads();

    int o;
    if (t == 0) {
        o = 0;
    } else {
        float d = cdf_d[t];
        int lo = 0, hi = BINS;           // searchsorted 'left' in [0,256]
        while (lo < hi) {
            int m = (lo + hi) >> 1;
            if (cdf_r[m] < d) lo = m + 1; else hi = m;
        }
        int cand = lo > 1 ? lo : 1;
        bool ok = (cand <= BINS - 1) && (d >= cdf_r[cand - 1]);
        if (!ok) atomicMin(&firstFail, t);
        o = cand;
    }
    __syncthreads();
    if (t >= firstFail) o = BINS - 1;
    if (t == BINS - 1) o = BINS - 1;
    slut[t] = (float)o / 255.0f;
    __syncthreads();

    const float4* in4 = reinterpret_cast<const float4*>(dst) + (size_t)bc * n4_per_row;
    float4* out4 = reinterpret_cast<float4*>(out) + (size_t)bc * n4_per_row;
    const int gsz = gridDim.x * blockDim.x;

    #pragma unroll 4
    for (int i = blockIdx.x * blockDim.x + t; i < n4_per_row; i += gsz) {
        float4 v = in4[i];
        float4 o4;
        o4.x = slut[min(max((int)(v.x * 255.0f), 0), BINS - 1)];
        o4.y = slut[min(max((int)(v.y * 255.0f), 0), BINS - 1)];
        o4.z = slut[min(max((int)(v.z * 255.0f), 0), BINS - 1)];
        o4.w = slut[min(max((int)(v.w * 255.0f), 0), BINS - 1)];
        out4[i] = o4;
    }
}

extern "C" void kernel_launch(void* const* d_in, const int* in_sizes, int n_in,
                              void* d_out, int out_size, void* d_ws, size_t ws_size,
                              hipStream_t stream) {
    const float* dst  = (const float*)d_in[0];
    const float* refp = (const float*)d_in[1];
    float* out = (float*)d_out;

    const int total = in_sizes[0];          // 8*3*1024*1024
    const int hw = total / BC_N;            // 1048576
    const int n4 = hw >> 2;                 // 262144 float4 per row

    // workspace: [hist_dst 24x256 u32][hist_ref 24x256 u32] = 48 KB
    unsigned int* hist = (unsigned int*)d_ws;
    hipMemsetAsync(d_ws, 0, (size_t)2 * BC_N * BINS * sizeof(unsigned int), stream);

    dim3 hg(CH, BC_N, 2);
    hm_hist<<<hg, dim3(256), 0, stream>>>(dst, refp, hist, n4);

    dim3 ag(64, BC_N);
    hm_apply<<<ag, dim3(256), 0, stream>>>(dst, hist, out, n4);
}

// Round 8
// 80.452 us; speedup vs baseline: 1.7484x; 1.7484x over previous
//
#include <hip/hip_runtime.h>

#define BINS 256
#define BC_N 24   // B*C = 8*3
#define C_N  3
#define CH   32   // blocks per (row,img): 32*24*2 = 1536 blocks = 6/CU exactly
#define DEPTH 6   // pipeline slots per wave (6 KB in flight per wave)
#define WAVES 4

typedef float f32x4 __attribute__((ext_vector_type(4)));

// ---------------------------------------------------------------------------
// Kernel 1: per-row 256-bin histograms of dst and ref.
// grid = (CH, 24 rows, 2 images), block = 256 (4 waves).
//
// r2-r4 post-mortem: the ~70us wall was MLP starvation (2.87 TB/s = ~6 loads
// in flight/wave; compiler refused deeper register batching, VGPR=28), NOT
// LDS-atomic throughput (~10-15us/CU). This version forces deep MLP with
// global_load_lds into a wave-private 6-slot LDS ring: counted vmcnt(5)
// (never 0 in steady state), asm ds_read_b128 + lgkmcnt(0) fused in one
// volatile block (rule #18), refill same slot, 4x ds_add counts.
// 24 waves/CU x 6 KB = 144 KB in flight/CU -> BW-bound.
// bin = floor(x*256) == trunc for x in [0,1); clamped for fp safety.
// ---------------------------------------------------------------------------
__global__ __launch_bounds__(256) void hm_hist(const float* __restrict__ dst,
                                               const float* __restrict__ refp,
                                               unsigned int* __restrict__ hist,
                                               int n4_per_row) {
    __shared__ __align__(16) float stage[WAVES * DEPTH * 256];  // 24 KB staging
    __shared__ unsigned int shist[BINS];                        // 1 KB counts

    const int t = threadIdx.x;
    const int w = t >> 6;          // wave id
    const int l = t & 63;          // lane id

    shist[t] = 0u;
    __syncthreads();

    const int row = blockIdx.y;
    const float* img = blockIdx.z ? refp : dst;
    const float4* p4 = reinterpret_cast<const float4*>(img) + (size_t)row * n4_per_row;

    const int span  = n4_per_row / CH;    // 8192 float4, contiguous per block
    const int its   = span >> 8;          // 32 chunks of 256 float4 (64/wave)
    const int base4 = blockIdx.x * span;

    float* wavebase = stage + w * (DEPTH * 256);
    const unsigned ldsw =
        (unsigned)(size_t)(__attribute__((address_space(3))) void*)wavebase;
    const unsigned myoff = ldsw + (unsigned)(l * 16);   // this lane's staged bytes

    // prologue: fill the ring (DEPTH chunks in flight)
    for (int k = 0; k < DEPTH && k < its; ++k) {
        const float4* gp = p4 + base4 + (k << 8) + (w << 6) + l;
        __builtin_amdgcn_global_load_lds(
            (const __attribute__((address_space(1))) void*)gp,
            (__attribute__((address_space(3))) void*)(wavebase + k * 256),
            16, 0, 0);
    }

    int slot = 0;
    int k = 0;
    // steady state: counted vmcnt (DEPTH-1 = 5), consume oldest, refill slot
    for (; k < its - DEPTH; ++k) {
        asm volatile("s_waitcnt vmcnt(5)");
        f32x4 v;
        asm volatile("ds_read_b128 %0, %1\n\ts_waitcnt lgkmcnt(0)"
                     : "=v"(v)
                     : "v"(myoff + (unsigned)(slot << 10)));
        const float4* gp = p4 + base4 + ((k + DEPTH) << 8) + (w << 6) + l;
        __builtin_amdgcn_global_load_lds(
            (const __attribute__((address_space(1))) void*)gp,
            (__attribute__((address_space(3))) void*)(wavebase + slot * 256),
            16, 0, 0);
        int b0 = min(max((int)(v.x * 256.0f), 0), BINS - 1);
        int b1 = min(max((int)(v.y * 256.0f), 0), BINS - 1);
        int b2 = min(max((int)(v.z * 256.0f), 0), BINS - 1);
        int b3 = min(max((int)(v.w * 256.0f), 0), BINS - 1);
        atomicAdd(&shist[b0], 1u);
        atomicAdd(&shist[b1], 1u);
        atomicAdd(&shist[b2], 1u);
        atomicAdd(&shist[b3], 1u);
        slot = (slot + 1 == DEPTH) ? 0 : slot + 1;
    }
    // tail: drain once, consume remaining slots without waits
    asm volatile("s_waitcnt vmcnt(0)");
    for (; k < its; ++k) {
        f32x4 v;
        asm volatile("ds_read_b128 %0, %1\n\ts_waitcnt lgkmcnt(0)"
                     : "=v"(v)
                     : "v"(myoff + (unsigned)(slot << 10)));
        int b0 = min(max((int)(v.x * 256.0f), 0), BINS - 1);
        int b1 = min(max((int)(v.y * 256.0f), 0), BINS - 1);
        int b2 = min(max((int)(v.z * 256.0f), 0), BINS - 1);
        int b3 = min(max((int)(v.w * 256.0f), 0), BINS - 1);
        atomicAdd(&shist[b0], 1u);
        atomicAdd(&shist[b1], 1u);
        atomicAdd(&shist[b2], 1u);
        atomicAdd(&shist[b3], 1u);
        slot = (slot + 1 == DEPTH) ? 0 : slot + 1;
    }

    __syncthreads();
    unsigned int* g = hist + ((size_t)blockIdx.z * BC_N + row) * BINS;
    atomicAdd(&g[t], shist[t]);
}

// ---------------------------------------------------------------------------
// Kernel 2 (r4 verbatim): per row, integer inclusive scan (exact: partials
// <= 2^20) -> CDF = cum / max(total,1e-12) (division by 2^20 exact ->
// bit-identical to np's sequential fp32 cumsum of count/total) -> transfer
// table via parallelized two-pointer:
//   s_i = searchsorted(cdf_ref, cdf_dst[i]); table[i] = max(1, s_i) before
//   first failure; first fail poisons all later entries to 255.
// table[0]=0, table[255]=255. lut = table / 255.0f.
// grid = 24 blocks, block = 256.
// ---------------------------------------------------------------------------
__global__ __launch_bounds__(256) void hm_table(const unsigned int* __restrict__ hist,
                                                float* __restrict__ lut) {
    __shared__ unsigned int sd[BINS], sr[BINS];
    __shared__ float cdf_d[BINS], cdf_r[BINS];
    __shared__ int firstFail;

    const int r = blockIdx.x;
    const int t = threadIdx.x;

    unsigned int xd = hist[(size_t)r * BINS + t];
    unsigned int xr = hist[(size_t)(BC_N + r) * BINS + t];
    if (t == 0) firstFail = BINS;
    sd[t] = xd; sr[t] = xr;
    __syncthreads();

    #pragma unroll
    for (int off = 1; off < BINS; off <<= 1) {
        unsigned int yd = (t >= off) ? sd[t - off] : 0u;
        unsigned int yr = (t >= off) ? sr[t - off] : 0u;
        __syncthreads();
        xd += yd; xr += yr;
        sd[t] = xd; sr[t] = xr;
        __syncthreads();
    }
    float totd = fmaxf((float)sd[BINS - 1], 1e-12f);
    float totr = fmaxf((float)sr[BINS - 1], 1e-12f);
    cdf_d[t] = (float)xd / totd;
    cdf_r[t] = (float)xr / totr;
    __syncthreads();

    int out;
    if (t == 0) {
        out = 0;
    } else {
        float d = cdf_d[t];
        int lo = 0, hi = BINS;           // searchsorted 'left' in [0,256]
        while (lo < hi) {
            int m = (lo + hi) >> 1;
            if (cdf_r[m] < d) lo = m + 1; else hi = m;
        }
        int cand = lo > 1 ? lo : 1;
        bool ok = (cand <= BINS - 1) && (d >= cdf_r[cand - 1]);
        if (!ok) atomicMin(&firstFail, t);
        out = cand;
    }
    __syncthreads();

    if (t >= firstFail) out = BINS - 1;
    if (t == BINS - 1) out = BINS - 1;
    lut[(size_t)r * BINS + t] = (float)out / 255.0f;
}

// ---------------------------------------------------------------------------
// Kernel 3 (r4 verbatim): apply LUT; preserves the reference's row_sel = b*c
// indexing bug. pix = clip(trunc(dst*255), 0, 255). grid = (64, 24).
// ---------------------------------------------------------------------------
__global__ __launch_bounds__(256) void hm_apply(const float* __restrict__ dst,
                                                const float* __restrict__ lut,
                                                float* __restrict__ out,
                                                int n4_per_row) {
    __shared__ float slut[BINS];
    const int bc = blockIdx.y;
    const int b = bc / C_N;
    const int c = bc - b * C_N;
    const int row = b * c;               // <-- preserved bug: b*c, not b*C+c
    const int t = threadIdx.x;

    slut[t] = lut[(size_t)row * BINS + t];
    __syncthreads();

    const float4* in4 = reinterpret_cast<const float4*>(dst) + (size_t)bc * n4_per_row;
    float4* out4 = reinterpret_cast<float4*>(out) + (size_t)bc * n4_per_row;
    const int gsz = gridDim.x * blockDim.x;

    #pragma unroll 4
    for (int i = blockIdx.x * blockDim.x + t; i < n4_per_row; i += gsz) {
        float4 v = in4[i];
        float4 o;
        o.x = slut[min(max((int)(v.x * 255.0f), 0), BINS - 1)];
        o.y = slut[min(max((int)(v.y * 255.0f), 0), BINS - 1)];
        o.z = slut[min(max((int)(v.z * 255.0f), 0), BINS - 1)];
        o.w = slut[min(max((int)(v.w * 255.0f), 0), BINS - 1)];
        out4[i] = o;
    }
}

extern "C" void kernel_launch(void* const* d_in, const int* in_sizes, int n_in,
                              void* d_out, int out_size, void* d_ws, size_t ws_size,
                              hipStream_t stream) {
    const float* dst  = (const float*)d_in[0];
    const float* refp = (const float*)d_in[1];
    float* out = (float*)d_out;

    const int total = in_sizes[0];          // 8*3*1024*1024
    const int hw = total / BC_N;            // 1048576
    const int n4 = hw >> 2;                 // 262144 float4 per row

    // workspace: [hist_dst 24x256 u32][hist_ref 24x256 u32][lut 24x256 f32]
    unsigned int* hist = (unsigned int*)d_ws;
    float* lut = (float*)((char*)d_ws + (size_t)2 * BC_N * BINS * sizeof(unsigned int));

    hipMemsetAsync(d_ws, 0, (size_t)2 * BC_N * BINS * sizeof(unsigned int), stream);

    dim3 hg(CH, BC_N, 2);
    hm_hist<<<hg, dim3(256), 0, stream>>>(dst, refp, hist, n4);

    hm_table<<<dim3(BC_N), dim3(256), 0, stream>>>(hist, lut);

    dim3 ag(64, BC_N);
    hm_apply<<<ag, dim3(256), 0, stream>>>(dst, lut, out, n4);
}

// Round 9
// 73.100 us; speedup vs baseline: 1.9242x; 1.1006x over previous
//
#include <hip/hip_runtime.h>

#define BINS 256
#define BC_N 24   // B*C = 8*3
#define C_N  3
#define NROWS 12  // the row_sel = b*c bug uses only rows {0..8,10,12,14}
#define CH   64   // blocks per (compact row, img): 64*12*2 = 1536 blocks = 6/CU
#define WAVES 4

// ---------------------------------------------------------------------------
// Kernel 1: 256-bin histograms for the 12 USED rows of dst and ref.
// grid = (CH, 12 compact rows, 2 images), block = 256 (4 waves).
//
// r2-r7 established: LDS ds_add processes ~1.1 lane-ops/cyc/CU regardless of
// banking/replication/DMA depth (82us wall for 50M px); ballot bit-slicing
// costs ~104us of pure VALU for 50M px (r6). Two fixes, multiplicative:
//  (a) reference's row_sel=b*c bug -> only rows {0..8,10,12,14} matter: 2x.
//  (b) split each batch across BOTH pipes: 4 float4 -> ds_add (fire-and-
//      forget, LDS unit), 4 float4 -> ballot+popc (VALU). Pipes overlap.
// bin = floor(x*256) == trunc for x in [0,1); min-clamp suffices (x>=0).
// ---------------------------------------------------------------------------
__global__ __launch_bounds__(256) void hm_hist(const float* __restrict__ dst,
                                               const float* __restrict__ refp,
                                               unsigned int* __restrict__ hist,
                                               int n4_per_row) {
    __shared__ unsigned int shist[BINS];          // atomic-path counts (1 KB)
    __shared__ unsigned int wsum[WAVES][BINS];    // ballot-path merge (4 KB)

    const int t = threadIdx.x;
    const int l = t & 63;
    const int w = t >> 6;

    shist[t] = 0u;
    __syncthreads();

    const int y = blockIdx.y;
    const int row = (y < 9) ? y : 2 * y - 8;      // {0..8,10,12,14}
    const float* img = blockIdx.z ? refp : dst;
    const float4* p = reinterpret_cast<const float4*>(img) + (size_t)row * n4_per_row;

    // XNOR selectors: bit l' of (B_j ^ t_j) == [bin(l')_j == l_j]
    const unsigned long long t0 = (l & 1)  ? 0ull : ~0ull;
    const unsigned long long t1 = (l & 2)  ? 0ull : ~0ull;
    const unsigned long long t2 = (l & 4)  ? 0ull : ~0ull;
    const unsigned long long t3 = (l & 8)  ? 0ull : ~0ull;
    const unsigned long long t4 = (l & 16) ? 0ull : ~0ull;
    const unsigned long long t5 = (l & 32) ? 0ull : ~0ull;
    unsigned int c0 = 0, c1 = 0, c2 = 0, c3 = 0;  // bins l, l+64, l+128, l+192

    auto grp = [&](float x) {                     // counts 64 px (one/lane) on VALU
        int bin = min((int)(x * 256.0f), BINS - 1);
        unsigned long long B0 = __ballot(bin & 1);
        unsigned long long B1 = __ballot(bin & 2);
        unsigned long long B2 = __ballot(bin & 4);
        unsigned long long B3 = __ballot(bin & 8);
        unsigned long long B4 = __ballot(bin & 16);
        unsigned long long B5 = __ballot(bin & 32);
        unsigned long long B6 = __ballot(bin & 64);
        unsigned long long B7 = __ballot(bin & 128);
        unsigned long long m = (B0 ^ t0) & (B1 ^ t1) & (B2 ^ t2)
                             & (B3 ^ t3) & (B4 ^ t4) & (B5 ^ t5);
        unsigned long long a = m & ~B7, b = m & B7;
        c0 += (unsigned)__popcll(a & ~B6);
        c1 += (unsigned)__popcll(a &  B6);
        c2 += (unsigned)__popcll(b & ~B6);
        c3 += (unsigned)__popcll(b &  B6);
    };
    auto atom = [&](float x) {
        atomicAdd(&shist[min((int)(x * 256.0f), BINS - 1)], 1u);
    };

    const int stride = CH * 256;                  // 16384 float4
    const int nfull = n4_per_row / (8 * stride);  // 2 for 1024x1024 rows
    int i = blockIdx.x * 256 + t;

    for (int it = 0; it < nfull; ++it, i += 8 * stride) {
        float4 v[8];
        #pragma unroll
        for (int k = 0; k < 8; ++k) v[k] = p[i + k * stride];
        __builtin_amdgcn_sched_barrier(0);        // all 8 loads issued first
        #pragma unroll
        for (int k = 0; k < 4; ++k) {             // LDS-atomic pipe half
            atom(v[k].x); atom(v[k].y); atom(v[k].z); atom(v[k].w);
        }
        #pragma unroll
        for (int k = 4; k < 8; ++k) {             // VALU-ballot pipe half
            grp(v[k].x); grp(v[k].y); grp(v[k].z); grp(v[k].w);
        }
    }
    // generic remainder (not taken for this shape); atomic path is exec-safe
    for (int j = nfull * 8 * stride + blockIdx.x * 256 + t; j < n4_per_row; j += stride) {
        float4 v = p[j];
        atom(v.x); atom(v.y); atom(v.z); atom(v.w);
    }
    __syncthreads();

    wsum[w][l]       = c0;
    wsum[w][l + 64]  = c1;
    wsum[w][l + 128] = c2;
    wsum[w][l + 192] = c3;
    __syncthreads();

    unsigned int s = shist[t] + wsum[0][t] + wsum[1][t] + wsum[2][t] + wsum[3][t];
    unsigned int* g = hist + ((size_t)blockIdx.z * NROWS + y) * BINS;
    atomicAdd(&g[t], s);
}

// ---------------------------------------------------------------------------
// Kernel 2 (r4-validated, compact rows): integer Hillis-Steele scan (exact:
// partials <= 2^20) -> CDF = cum/max(total,1e-12) (exact /2^20 -> bit-
// identical to np's sequential fp32 cumsum) -> parallelized two-pointer:
//   s_i = searchsorted(cdf_ref, cdf_dst[i]); table[i]=max(1,s_i) before the
//   first failure; first fail poisons all later entries to 255.
// table[0]=0, table[255]=255. lut = table/255. grid = 12 blocks.
// ---------------------------------------------------------------------------
__global__ __launch_bounds__(256) void hm_table(const unsigned int* __restrict__ hist,
                                                float* __restrict__ lut) {
    __shared__ unsigned int sd[BINS], sr[BINS];
    __shared__ float cdf_d[BINS], cdf_r[BINS];
    __shared__ int firstFail;

    const int r = blockIdx.x;                     // compact row
    const int t = threadIdx.x;

    unsigned int xd = hist[(size_t)r * BINS + t];
    unsigned int xr = hist[(size_t)(NROWS + r) * BINS + t];
    if (t == 0) firstFail = BINS;
    sd[t] = xd; sr[t] = xr;
    __syncthreads();

    #pragma unroll
    for (int off = 1; off < BINS; off <<= 1) {
        unsigned int yd = (t >= off) ? sd[t - off] : 0u;
        unsigned int yr = (t >= off) ? sr[t - off] : 0u;
        __syncthreads();
        xd += yd; xr += yr;
        sd[t] = xd; sr[t] = xr;
        __syncthreads();
    }
    float totd = fmaxf((float)sd[BINS - 1], 1e-12f);
    float totr = fmaxf((float)sr[BINS - 1], 1e-12f);
    cdf_d[t] = (float)xd / totd;
    cdf_r[t] = (float)xr / totr;
    __syncthreads();

    int out;
    if (t == 0) {
        out = 0;
    } else {
        float d = cdf_d[t];
        int lo = 0, hi = BINS;                    // searchsorted 'left' in [0,256]
        while (lo < hi) {
            int m = (lo + hi) >> 1;
            if (cdf_r[m] < d) lo = m + 1; else hi = m;
        }
        int cand = lo > 1 ? lo : 1;
        bool ok = (cand <= BINS - 1) && (d >= cdf_r[cand - 1]);
        if (!ok) atomicMin(&firstFail, t);
        out = cand;
    }
    __syncthreads();

    if (t >= firstFail) out = BINS - 1;
    if (t == BINS - 1) out = BINS - 1;
    lut[(size_t)r * BINS + t] = (float)out / 255.0f;
}

// ---------------------------------------------------------------------------
// Kernel 3 (r4-validated): apply LUT; preserves the reference's row_sel=b*c
// bug via compact-index mapping. pix = clip(trunc(dst*255),0,255).
// grid = (64, 24), block = 256.
// ---------------------------------------------------------------------------
__global__ __launch_bounds__(256) void hm_apply(const float* __restrict__ dst,
                                                const float* __restrict__ lut,
                                                float* __restrict__ out,
                                                int n4_per_row) {
    __shared__ float slut[BINS];
    const int bc = blockIdx.y;
    const int b = bc / C_N;
    const int c = bc - b * C_N;
    const int r = b * c;                          // <-- preserved bug
    const int cr = (r <= 8) ? r : 8 + ((r - 8) >> 1);   // compact index
    const int t = threadIdx.x;

    slut[t] = lut[(size_t)cr * BINS + t];
    __syncthreads();

    const float4* in4 = reinterpret_cast<const float4*>(dst) + (size_t)bc * n4_per_row;
    float4* out4 = reinterpret_cast<float4*>(out) + (size_t)bc * n4_per_row;
    const int gsz = gridDim.x * blockDim.x;

    #pragma unroll 4
    for (int i = blockIdx.x * blockDim.x + t; i < n4_per_row; i += gsz) {
        float4 v = in4[i];
        float4 o;
        o.x = slut[min(max((int)(v.x * 255.0f), 0), BINS - 1)];
        o.y = slut[min(max((int)(v.y * 255.0f), 0), BINS - 1)];
        o.z = slut[min(max((int)(v.z * 255.0f), 0), BINS - 1)];
        o.w = slut[min(max((int)(v.w * 255.0f), 0), BINS - 1)];
        out4[i] = o;
    }
}

extern "C" void kernel_launch(void* const* d_in, const int* in_sizes, int n_in,
                              void* d_out, int out_size, void* d_ws, size_t ws_size,
                              hipStream_t stream) {
    const float* dst  = (const float*)d_in[0];
    const float* refp = (const float*)d_in[1];
    float* out = (float*)d_out;

    const int total = in_sizes[0];          // 8*3*1024*1024
    const int hw = total / BC_N;            // 1048576
    const int n4 = hw >> 2;                 // 262144 float4 per row

    // workspace: [hist_dst 12x256 u32][hist_ref 12x256 u32][lut 12x256 f32]
    unsigned int* hist = (unsigned int*)d_ws;
    float* lut = (float*)((char*)d_ws + (size_t)2 * NROWS * BINS * sizeof(unsigned int));

    hipMemsetAsync(d_ws, 0, (size_t)2 * NROWS * BINS * sizeof(unsigned int), stream);

    dim3 hg(CH, NROWS, 2);
    hm_hist<<<hg, dim3(256), 0, stream>>>(dst, refp, hist, n4);

    hm_table<<<dim3(NROWS), dim3(256), 0, stream>>>(hist, lut);

    dim3 ag(64, BC_N);
    hm_apply<<<ag, dim3(256), 0, stream>>>(dst, lut, out, n4);
}

// Round 10
// 71.890 us; speedup vs baseline: 1.9566x; 1.0168x over previous
//
#include <hip/hip_runtime.h>

#define BINS 256
#define BC_N 24   // B*C = 8*3
#define C_N  3
#define NROWS 12  // the row_sel = b*c bug uses only rows {0..8,10,12,14}
#define CH   64   // blocks per (compact row, img): 64*12*2 = 1536 blocks = 6/CU

// ---------------------------------------------------------------------------
// Kernel 1: 256-bin histograms for the 12 USED rows of dst and ref.
// grid = (CH, 12 compact rows, 2 images), block = 256 (4 waves).
//
// WAVE-SPECIALIZED (r9 lesson: in-order issue makes per-wave pipe mixing
// ADDITIVE -- the ds_add queue backpressure stalls the wave before it reaches
// its ballot work). Waves 0-1: pure LDS-atomic counting (pipe runs at ~1
// lane-op/cyc/CU regardless of banking, r2-r8 invariant). Waves 2-3: pure
// VALU ballot bit-slicing (r6-validated, zero LDS in loop). 9:7 pixel split
// per measured pipe rates. Each block stores its partial histogram
// NON-atomically to its own slot: no memset, no global atomics.
// bin = floor(x*256) == trunc for x in [0,1); min-clamp suffices (x>=0).
// ---------------------------------------------------------------------------
__global__ __launch_bounds__(256) void hm_hist(const float* __restrict__ dst,
                                               const float* __restrict__ refp,
                                               unsigned int* __restrict__ part,
                                               int n4_per_row) {
    __shared__ unsigned int shist[BINS];        // atomic-wave counts
    __shared__ unsigned int wsum[2][BINS];      // ballot-wave counts

    const int t = threadIdx.x;
    const int l = t & 63;
    const int w = t >> 6;

    shist[t] = 0u;
    wsum[0][t] = 0u; wsum[1][t] = 0u;
    __syncthreads();

    const int y = blockIdx.y;
    const int row = (y < 9) ? y : 2 * y - 8;    // {0..8,10,12,14}
    const float* img = blockIdx.z ? refp : dst;
    const int span = n4_per_row / CH;           // 4096 float4 per block
    const float4* p = reinterpret_cast<const float4*>(img)
                    + (size_t)row * n4_per_row + (size_t)blockIdx.x * span;

    const int nsl = span >> 6;                  // 64 slices of 64 float4
    const int NA  = (nsl * 9) >> 4;             // 36 slices -> atomic waves

    if (w < 2) {
        // ----- atomic-pipe waves: fire-and-forget ds_add -----
        for (int s = w; s < NA; s += 2) {
            float4 v = p[(s << 6) + l];
            atomicAdd(&shist[min((int)(v.x * 256.0f), BINS - 1)], 1u);
            atomicAdd(&shist[min((int)(v.y * 256.0f), BINS - 1)], 1u);
            atomicAdd(&shist[min((int)(v.z * 256.0f), BINS - 1)], 1u);
            atomicAdd(&shist[min((int)(v.w * 256.0f), BINS - 1)], 1u);
        }
        // generic tails (empty for this shape); exec-masked atomics are safe
        if (w == 0) {
            for (int j = (nsl << 6) + l; j < span; j += 64) {
                float4 v = p[j];
                atomicAdd(&shist[min((int)(v.x * 256.0f), BINS - 1)], 1u);
                atomicAdd(&shist[min((int)(v.y * 256.0f), BINS - 1)], 1u);
                atomicAdd(&shist[min((int)(v.z * 256.0f), BINS - 1)], 1u);
                atomicAdd(&shist[min((int)(v.w * 256.0f), BINS - 1)], 1u);
            }
            if (blockIdx.x == CH - 1) {
                for (int j = CH * span + l; j < n4_per_row; j += 64) {
                    const float4* pr = reinterpret_cast<const float4*>(img)
                                     + (size_t)row * n4_per_row;
                    float4 v = pr[j];
                    atomicAdd(&shist[min((int)(v.x * 256.0f), BINS - 1)], 1u);
                    atomicAdd(&shist[min((int)(v.y * 256.0f), BINS - 1)], 1u);
                    atomicAdd(&shist[min((int)(v.z * 256.0f), BINS - 1)], 1u);
                    atomicAdd(&shist[min((int)(v.w * 256.0f), BINS - 1)], 1u);
                }
            }
        }
    } else {
        // ----- VALU ballot waves: zero LDS in the hot loop -----
        const unsigned long long t0 = (l & 1)  ? 0ull : ~0ull;
        const unsigned long long t1 = (l & 2)  ? 0ull : ~0ull;
        const unsigned long long t2 = (l & 4)  ? 0ull : ~0ull;
        const unsigned long long t3 = (l & 8)  ? 0ull : ~0ull;
        const unsigned long long t4 = (l & 16) ? 0ull : ~0ull;
        const unsigned long long t5 = (l & 32) ? 0ull : ~0ull;
        unsigned int c0 = 0, c1 = 0, c2 = 0, c3 = 0;  // bins l,l+64,l+128,l+192

        auto grp = [&](float x) {
            int bin = min((int)(x * 256.0f), BINS - 1);
            unsigned long long B0 = __ballot(bin & 1);
            unsigned long long B1 = __ballot(bin & 2);
            unsigned long long B2 = __ballot(bin & 4);
            unsigned long long B3 = __ballot(bin & 8);
            unsigned long long B4 = __ballot(bin & 16);
            unsigned long long B5 = __ballot(bin & 32);
            unsigned long long B6 = __ballot(bin & 64);
            unsigned long long B7 = __ballot(bin & 128);
            unsigned long long m = (B0 ^ t0) & (B1 ^ t1) & (B2 ^ t2)
                                 & (B3 ^ t3) & (B4 ^ t4) & (B5 ^ t5);
            unsigned long long a = m & ~B7, b = m & B7;
            c0 += (unsigned)__popcll(a & ~B6);
            c1 += (unsigned)__popcll(a &  B6);
            c2 += (unsigned)__popcll(b & ~B6);
            c3 += (unsigned)__popcll(b &  B6);
        };

        int s = NA + (w - 2);
        if (s < nsl) {
            float4 v = p[(s << 6) + l];
            for (; s + 2 < nsl; s += 2) {
                float4 nv = p[((s + 2) << 6) + l];    // 1-deep prefetch
                __builtin_amdgcn_sched_barrier(0);     // keep load above grps
                grp(v.x); grp(v.y); grp(v.z); grp(v.w);
                v = nv;
            }
            grp(v.x); grp(v.y); grp(v.z); grp(v.w);
        }
        wsum[w - 2][l]       = c0;
        wsum[w - 2][l + 64]  = c1;
        wsum[w - 2][l + 128] = c2;
        wsum[w - 2][l + 192] = c3;
    }
    __syncthreads();

    // non-atomic per-block partial store (no pre-zero, no global atomics)
    unsigned int sv = shist[t] + wsum[0][t] + wsum[1][t];
    part[(((size_t)blockIdx.z * NROWS + y) * CH + blockIdx.x) * BINS + t] = sv;
}

// ---------------------------------------------------------------------------
// Kernel 2: sum the CH per-block partials (exact integers), then the
// r4-validated pipeline: integer Hillis-Steele scan (partials <= 2^20) ->
// CDF = cum/max(total,1e-12) (exact /2^20 -> bit-identical to np's
// sequential fp32 cumsum) -> parallelized two-pointer:
//   s_i = searchsorted(cdf_ref, cdf_dst[i]); table[i]=max(1,s_i) before the
//   first failure; first fail poisons all later entries to 255.
// table[0]=0, table[255]=255. lut = table/255. grid = 12 blocks.
// ---------------------------------------------------------------------------
__global__ __launch_bounds__(256) void hm_table(const unsigned int* __restrict__ part,
                                                float* __restrict__ lut) {
    __shared__ unsigned int sd[BINS], sr[BINS];
    __shared__ float cdf_d[BINS], cdf_r[BINS];
    __shared__ int firstFail;

    const int r = blockIdx.x;                   // compact row
    const int t = threadIdx.x;

    const unsigned int* pd = part + ((size_t)0 * NROWS + r) * CH * BINS;
    const unsigned int* pr = part + ((size_t)1 * NROWS + r) * CH * BINS;
    unsigned int xd = 0, xr = 0;
    #pragma unroll 8
    for (int k = 0; k < CH; ++k) {
        xd += pd[k * BINS + t];
        xr += pr[k * BINS + t];
    }
    if (t == 0) firstFail = BINS;
    sd[t] = xd; sr[t] = xr;
    __syncthreads();

    #pragma unroll
    for (int off = 1; off < BINS; off <<= 1) {
        unsigned int yd = (t >= off) ? sd[t - off] : 0u;
        unsigned int yr = (t >= off) ? sr[t - off] : 0u;
        __syncthreads();
        xd += yd; xr += yr;
        sd[t] = xd; sr[t] = xr;
        __syncthreads();
    }
    float totd = fmaxf((float)sd[BINS - 1], 1e-12f);
    float totr = fmaxf((float)sr[BINS - 1], 1e-12f);
    cdf_d[t] = (float)xd / totd;
    cdf_r[t] = (float)xr / totr;
    __syncthreads();

    int out;
    if (t == 0) {
        out = 0;
    } else {
        float d = cdf_d[t];
        int lo = 0, hi = BINS;                  // searchsorted 'left' in [0,256]
        while (lo < hi) {
            int m = (lo + hi) >> 1;
            if (cdf_r[m] < d) lo = m + 1; else hi = m;
        }
        int cand = lo > 1 ? lo : 1;
        bool ok = (cand <= BINS - 1) && (d >= cdf_r[cand - 1]);
        if (!ok) atomicMin(&firstFail, t);
        out = cand;
    }
    __syncthreads();

    if (t >= firstFail) out = BINS - 1;
    if (t == BINS - 1) out = BINS - 1;
    lut[(size_t)r * BINS + t] = (float)out / 255.0f;
}

// ---------------------------------------------------------------------------
// Kernel 3 (r4-validated): apply LUT; preserves the reference's row_sel=b*c
// bug via compact-index mapping. pix = clip(trunc(dst*255),0,255).
// grid = (64, 24), block = 256.
// ---------------------------------------------------------------------------
__global__ __launch_bounds__(256) void hm_apply(const float* __restrict__ dst,
                                                const float* __restrict__ lut,
                                                float* __restrict__ out,
                                                int n4_per_row) {
    __shared__ float slut[BINS];
    const int bc = blockIdx.y;
    const int b = bc / C_N;
    const int c = bc - b * C_N;
    const int r = b * c;                        // <-- preserved bug
    const int cr = (r <= 8) ? r : 8 + ((r - 8) >> 1);   // compact index
    const int t = threadIdx.x;

    slut[t] = lut[(size_t)cr * BINS + t];
    __syncthreads();

    const float4* in4 = reinterpret_cast<const float4*>(dst) + (size_t)bc * n4_per_row;
    float4* out4 = reinterpret_cast<float4*>(out) + (size_t)bc * n4_per_row;
    const int gsz = gridDim.x * blockDim.x;

    #pragma unroll 4
    for (int i = blockIdx.x * blockDim.x + t; i < n4_per_row; i += gsz) {
        float4 v = in4[i];
        float4 o;
        o.x = slut[min(max((int)(v.x * 255.0f), 0), BINS - 1)];
        o.y = slut[min(max((int)(v.y * 255.0f), 0), BINS - 1)];
        o.z = slut[min(max((int)(v.z * 255.0f), 0), BINS - 1)];
        o.w = slut[min(max((int)(v.w * 255.0f), 0), BINS - 1)];
        out4[i] = o;
    }
}

extern "C" void kernel_launch(void* const* d_in, const int* in_sizes, int n_in,
                              void* d_out, int out_size, void* d_ws, size_t ws_size,
                              hipStream_t stream) {
    const float* dst  = (const float*)d_in[0];
    const float* refp = (const float*)d_in[1];
    float* out = (float*)d_out;

    const int total = in_sizes[0];          // 8*3*1024*1024
    const int hw = total / BC_N;            // 1048576
    const int n4 = hw >> 2;                 // 262144 float4 per row

    // workspace: [part 2 x 12 x 64 x 256 u32 = 1.5 MB][lut 12x256 f32]
    unsigned int* part = (unsigned int*)d_ws;
    float* lut = (float*)((char*)d_ws + (size_t)2 * NROWS * CH * BINS * sizeof(unsigned int));

    dim3 hg(CH, NROWS, 2);
    hm_hist<<<hg, dim3(256), 0, stream>>>(dst, refp, part, n4);

    hm_table<<<dim3(NROWS), dim3(256), 0, stream>>>(part, lut);

    dim3 ag(64, BC_N);
    hm_apply<<<ag, dim3(256), 0, stream>>>(dst, lut, out, n4);
}

// Round 11
// 70.053 us; speedup vs baseline: 2.0079x; 1.0262x over previous
//
#include <hip/hip_runtime.h>

#define BINS 256
#define BC_N 24   // B*C = 8*3
#define C_N  3
#define NROWS 12  // the row_sel = b*c bug uses only rows {0..8,10,12,14}
#define CH   32   // hist blocks per (row,img): 32*12*2 = 768 = 3/CU (8-wave blocks)
#define ACH  128  // apply chunks: 128*24 = 3072 blocks = 12/CU... (wave-capped 8)

// ---------------------------------------------------------------------------
// Kernel 1: 256-bin histograms for the 12 USED rows of dst and ref.
// grid = (CH, 12 compact rows, 2 images), block = 512 (8 waves).
//
// r10 lesson: ds_add rate scales with feeder waves (24 waves/CU -> 1.08
// lane-ops/cyc/CU, 12 -> ~0.55). This block shape restores saturation:
// 3 blocks/CU x 8 waves = 24 resident waves; 5 waves/block feed the LDS-
// atomic pipe (15/CU issuing back-to-back ds_add with 3-deep batched loads),
// 3 waves/block run the r6-validated VALU ballot path. 59:41 pixel split
// matches measured pipe rates; the two pipes overlap cross-wave (m114).
// bin = floor(x*256) == trunc for x in [0,1).
// ---------------------------------------------------------------------------
__global__ __launch_bounds__(512) void hm_hist(const float* __restrict__ dst,
                                               const float* __restrict__ refp,
                                               unsigned int* __restrict__ part,
                                               int n4_per_row) {
    __shared__ unsigned int shist[BINS];        // atomic-wave counts
    __shared__ unsigned int wsum[3][BINS];      // ballot-wave counts

    const int t = threadIdx.x;
    const int l = t & 63;
    const int w = t >> 6;                       // 0..7

    if (t < BINS) shist[t] = 0u;
    __syncthreads();

    const int y = blockIdx.y;
    const int row = (y < 9) ? y : 2 * y - 8;    // {0..8,10,12,14}
    const float* img = blockIdx.z ? refp : dst;
    const int span = n4_per_row / CH;           // 8192 float4 per block
    const float4* p = reinterpret_cast<const float4*>(img)
                    + (size_t)row * n4_per_row + (size_t)blockIdx.x * span;

    const int nsl = span >> 6;                  // 128 slices of 64 float4
    const int na  = (nsl * 75) >> 7;            // 75 slices -> atomic pipe (59%)

    if (w < 5) {
        // ----- atomic-pipe feeder waves: contiguous slice runs, 3-deep MLP -----
        const int per = na / 5;
        const int rem = na - per * 5;
        int s   = w * per + min(w, rem);
        int cnt = per + (w < rem ? 1 : 0);
        for (; cnt >= 3; cnt -= 3, s += 3) {
            float4 v0 = p[((s + 0) << 6) + l];
            float4 v1 = p[((s + 1) << 6) + l];
            float4 v2 = p[((s + 2) << 6) + l];
            __builtin_amdgcn_sched_barrier(0);
            atomicAdd(&shist[min((int)(v0.x * 256.0f), 255)], 1u);
            atomicAdd(&shist[min((int)(v0.y * 256.0f), 255)], 1u);
            atomicAdd(&shist[min((int)(v0.z * 256.0f), 255)], 1u);
            atomicAdd(&shist[min((int)(v0.w * 256.0f), 255)], 1u);
            atomicAdd(&shist[min((int)(v1.x * 256.0f), 255)], 1u);
            atomicAdd(&shist[min((int)(v1.y * 256.0f), 255)], 1u);
            atomicAdd(&shist[min((int)(v1.z * 256.0f), 255)], 1u);
            atomicAdd(&shist[min((int)(v1.w * 256.0f), 255)], 1u);
            atomicAdd(&shist[min((int)(v2.x * 256.0f), 255)], 1u);
            atomicAdd(&shist[min((int)(v2.y * 256.0f), 255)], 1u);
            atomicAdd(&shist[min((int)(v2.z * 256.0f), 255)], 1u);
            atomicAdd(&shist[min((int)(v2.w * 256.0f), 255)], 1u);
        }
        for (; cnt > 0; --cnt, ++s) {
            float4 v = p[(s << 6) + l];
            atomicAdd(&shist[min((int)(v.x * 256.0f), 255)], 1u);
            atomicAdd(&shist[min((int)(v.y * 256.0f), 255)], 1u);
            atomicAdd(&shist[min((int)(v.z * 256.0f), 255)], 1u);
            atomicAdd(&shist[min((int)(v.w * 256.0f), 255)], 1u);
        }
        // generic remainders (empty for this shape); exec-masked atomics safe
        if (w == 0) {
            for (int j = (nsl << 6) + l; j < span; j += 64) {
                float4 v = p[j];
                atomicAdd(&shist[min((int)(v.x * 256.0f), 255)], 1u);
                atomicAdd(&shist[min((int)(v.y * 256.0f), 255)], 1u);
                atomicAdd(&shist[min((int)(v.z * 256.0f), 255)], 1u);
                atomicAdd(&shist[min((int)(v.w * 256.0f), 255)], 1u);
            }
            if (blockIdx.x == CH - 1) {
                const float4* pr = reinterpret_cast<const float4*>(img)
                                 + (size_t)row * n4_per_row;
                for (int j = CH * span + l; j < n4_per_row; j += 64) {
                    float4 v = pr[j];
                    atomicAdd(&shist[min((int)(v.x * 256.0f), 255)], 1u);
                    atomicAdd(&shist[min((int)(v.y * 256.0f), 255)], 1u);
                    atomicAdd(&shist[min((int)(v.z * 256.0f), 255)], 1u);
                    atomicAdd(&shist[min((int)(v.w * 256.0f), 255)], 1u);
                }
            }
        }
    } else {
        // ----- VALU ballot waves (zero LDS in hot loop), strided slices -----
        const unsigned long long t0 = (l & 1)  ? 0ull : ~0ull;
        const unsigned long long t1 = (l & 2)  ? 0ull : ~0ull;
        const unsigned long long t2 = (l & 4)  ? 0ull : ~0ull;
        const unsigned long long t3 = (l & 8)  ? 0ull : ~0ull;
        const unsigned long long t4 = (l & 16) ? 0ull : ~0ull;
        const unsigned long long t5 = (l & 32) ? 0ull : ~0ull;
        unsigned int c0 = 0, c1 = 0, c2 = 0, c3 = 0;  // bins l,l+64,l+128,l+192

        auto grp = [&](float x) {
            int bin = min((int)(x * 256.0f), 255);
            unsigned long long B0 = __ballot(bin & 1);
            unsigned long long B1 = __ballot(bin & 2);
            unsigned long long B2 = __ballot(bin & 4);
            unsigned long long B3 = __ballot(bin & 8);
            unsigned long long B4 = __ballot(bin & 16);
            unsigned long long B5 = __ballot(bin & 32);
            unsigned long long B6 = __ballot(bin & 64);
            unsigned long long B7 = __ballot(bin & 128);
            unsigned long long m = (B0 ^ t0) & (B1 ^ t1) & (B2 ^ t2)
                                 & (B3 ^ t3) & (B4 ^ t4) & (B5 ^ t5);
            unsigned long long a = m & ~B7, b = m & B7;
            c0 += (unsigned)__popcll(a & ~B6);
            c1 += (unsigned)__popcll(a &  B6);
            c2 += (unsigned)__popcll(b & ~B6);
            c3 += (unsigned)__popcll(b &  B6);
        };

        int s = na + (w - 5);
        if (s < nsl) {
            float4 v = p[(s << 6) + l];
            for (; s + 3 < nsl; s += 3) {
                float4 nv = p[((s + 3) << 6) + l];    // 1-deep prefetch
                __builtin_amdgcn_sched_barrier(0);
                grp(v.x); grp(v.y); grp(v.z); grp(v.w);
                v = nv;
            }
            grp(v.x); grp(v.y); grp(v.z); grp(v.w);
        }
        wsum[w - 5][l]       = c0;                    // unconditional write
        wsum[w - 5][l + 64]  = c1;
        wsum[w - 5][l + 128] = c2;
        wsum[w - 5][l + 192] = c3;
    }
    __syncthreads();

    if (t < BINS) {
        unsigned int sv = shist[t] + wsum[0][t] + wsum[1][t] + wsum[2][t];
        part[(((size_t)blockIdx.z * NROWS + y) * CH + blockIdx.x) * BINS + t] = sv;
    }
}

// ---------------------------------------------------------------------------
// Kernel 2: sum CH per-block partials (exact integers), then the r4-validated
// pipeline: integer Hillis-Steele scan (partials <= 2^20) -> CDF =
// cum/max(total,1e-12) (exact /2^20 -> bit-identical to np's sequential fp32
// cumsum) -> parallelized two-pointer:
//   s_i = searchsorted(cdf_ref, cdf_dst[i]); table[i]=max(1,s_i) before the
//   first failure; first fail poisons all later entries to 255.
// table[0]=0, table[255]=255. lut = table/255. grid = 12 blocks.
// ---------------------------------------------------------------------------
__global__ __launch_bounds__(256) void hm_table(const unsigned int* __restrict__ part,
                                                float* __restrict__ lut) {
    __shared__ unsigned int sd[BINS], sr[BINS];
    __shared__ float cdf_d[BINS], cdf_r[BINS];
    __shared__ int firstFail;

    const int r = blockIdx.x;                   // compact row
    const int t = threadIdx.x;

    const unsigned int* pd = part + ((size_t)0 * NROWS + r) * CH * BINS;
    const unsigned int* pr = part + ((size_t)1 * NROWS + r) * CH * BINS;
    unsigned int xd = 0, xr = 0;
    #pragma unroll 8
    for (int k = 0; k < CH; ++k) {
        xd += pd[k * BINS + t];
        xr += pr[k * BINS + t];
    }
    if (t == 0) firstFail = BINS;
    sd[t] = xd; sr[t] = xr;
    __syncthreads();

    #pragma unroll
    for (int off = 1; off < BINS; off <<= 1) {
        unsigned int yd = (t >= off) ? sd[t - off] : 0u;
        unsigned int yr = (t >= off) ? sr[t - off] : 0u;
        __syncthreads();
        xd += yd; xr += yr;
        sd[t] = xd; sr[t] = xr;
        __syncthreads();
    }
    float totd = fmaxf((float)sd[BINS - 1], 1e-12f);
    float totr = fmaxf((float)sr[BINS - 1], 1e-12f);
    cdf_d[t] = (float)xd / totd;
    cdf_r[t] = (float)xr / totr;
    __syncthreads();

    int out;
    if (t == 0) {
        out = 0;
    } else {
        float d = cdf_d[t];
        int lo = 0, hi = BINS;                  // searchsorted 'left' in [0,256]
        while (lo < hi) {
            int m = (lo + hi) >> 1;
            if (cdf_r[m] < d) lo = m + 1; else hi = m;
        }
        int cand = lo > 1 ? lo : 1;
        bool ok = (cand <= BINS - 1) && (d >= cdf_r[cand - 1]);
        if (!ok) atomicMin(&firstFail, t);
        out = cand;
    }
    __syncthreads();

    if (t >= firstFail) out = BINS - 1;
    if (t == BINS - 1) out = BINS - 1;
    lut[(size_t)r * BINS + t] = (float)out / 255.0f;
}

// ---------------------------------------------------------------------------
// Kernel 3: apply LUT; preserves the reference's row_sel=b*c bug via compact
// mapping. pix = clip(trunc(dst*255),0,255). grid = (ACH=128, 24), block=256:
// 3072 blocks for full LDS-pipe + memory TLP, 2-deep load batching.
// ---------------------------------------------------------------------------
__global__ __launch_bounds__(256) void hm_apply(const float* __restrict__ dst,
                                                const float* __restrict__ lut,
                                                float* __restrict__ out,
                                                int n4_per_row) {
    __shared__ float slut[BINS];
    const int bc = blockIdx.y;
    const int b = bc / C_N;
    const int c = bc - b * C_N;
    const int r = b * c;                        // <-- preserved bug
    const int cr = (r <= 8) ? r : 8 + ((r - 8) >> 1);   // compact index
    const int t = threadIdx.x;

    slut[t] = lut[(size_t)cr * BINS + t];
    __syncthreads();

    const float4* in4 = reinterpret_cast<const float4*>(dst) + (size_t)bc * n4_per_row;
    float4* out4 = reinterpret_cast<float4*>(out) + (size_t)bc * n4_per_row;
    const int gsz = gridDim.x * 256;

    int i = blockIdx.x * 256 + t;
    for (; i + gsz < n4_per_row; i += 2 * gsz) {
        float4 v0 = in4[i];
        float4 v1 = in4[i + gsz];
        __builtin_amdgcn_sched_barrier(0);
        float4 o0, o1;
        o0.x = slut[min(max((int)(v0.x * 255.0f), 0), 255)];
        o0.y = slut[min(max((int)(v0.y * 255.0f), 0), 255)];
        o0.z = slut[min(max((int)(v0.z * 255.0f), 0), 255)];
        o0.w = slut[min(max((int)(v0.w * 255.0f), 0), 255)];
        o1.x = slut[min(max((int)(v1.x * 255.0f), 0), 255)];
        o1.y = slut[min(max((int)(v1.y * 255.0f), 0), 255)];
        o1.z = slut[min(max((int)(v1.z * 255.0f), 0), 255)];
        o1.w = slut[min(max((int)(v1.w * 255.0f), 0), 255)];
        out4[i] = o0;
        out4[i + gsz] = o1;
    }
    for (; i < n4_per_row; i += gsz) {
        float4 v = in4[i];
        float4 o;
        o.x = slut[min(max((int)(v.x * 255.0f), 0), 255)];
        o.y = slut[min(max((int)(v.y * 255.0f), 0), 255)];
        o.z = slut[min(max((int)(v.z * 255.0f), 0), 255)];
        o.w = slut[min(max((int)(v.w * 255.0f), 0), 255)];
        out4[i] = o;
    }
}

extern "C" void kernel_launch(void* const* d_in, const int* in_sizes, int n_in,
                              void* d_out, int out_size, void* d_ws, size_t ws_size,
                              hipStream_t stream) {
    const float* dst  = (const float*)d_in[0];
    const float* refp = (const float*)d_in[1];
    float* out = (float*)d_out;

    const int total = in_sizes[0];          // 8*3*1024*1024
    const int hw = total / BC_N;            // 1048576
    const int n4 = hw >> 2;                 // 262144 float4 per row

    // workspace: [part 2 x 12 x 32 x 256 u32 = 768 KB][lut 12x256 f32]
    unsigned int* part = (unsigned int*)d_ws;
    float* lut = (float*)((char*)d_ws + (size_t)2 * NROWS * CH * BINS * sizeof(unsigned int));

    dim3 hg(CH, NROWS, 2);
    hm_hist<<<hg, dim3(512), 0, stream>>>(dst, refp, part, n4);

    hm_table<<<dim3(NROWS), dim3(256), 0, stream>>>(part, lut);

    dim3 ag(ACH, BC_N);
    hm_apply<<<ag, dim3(256), 0, stream>>>(dst, lut, out, n4);
}